// Round 1
// baseline (728.825 us; speedup 1.0000x reference)
//
#include <hip/hip_runtime.h>
#include <math.h>

// PolylineNet fused kernel (fp32, correctness-first).
// One 128-thread block per polyline (B*N = 16384 blocks).
// thread c in [0,128) owns output column c of every layer.
// Intermediate [P=20, H=128] tiles live in LDS; LN stats via 40 lanes of wave 0.

#define PP 20     // points per polyline
#define CC 13     // input channels
#define HH 128    // hidden
#define OO 256    // output channels
#define HP 132    // padded LDS row stride (floats), 16B-aligned

__device__ __forceinline__ void ln_stats(const float* __restrict__ h,
                                         float* __restrict__ stats, int tid)
{
  // lanes 0..39 (all in wave 0): row = tid%20, half = tid/20 (cols half*64..+63)
  if (tid < 2 * PP) {
    const int r = tid % PP;
    const int half = tid / PP;
    const float4* hp = reinterpret_cast<const float4*>(h + r * HP + half * 64);
    float s = 0.f, q = 0.f;
#pragma unroll
    for (int i = 0; i < 16; i++) {
      const float4 v = hp[i];
      s += (v.x + v.y) + (v.z + v.w);
      q += (v.x * v.x + v.y * v.y) + (v.z * v.z + v.w * v.w);
    }
    const float s2 = __shfl(s, tid + PP, 64);
    const float q2 = __shfl(q, tid + PP, 64);
    if (half == 0) {
      const float mu  = (s + s2) * (1.0f / HH);
      const float var = (q + q2) * (1.0f / HH) - mu * mu;
      stats[2 * r]     = mu;
      stats[2 * r + 1] = 1.0f / sqrtf(var + 1e-5f);
    }
  }
}

// acc[r] += sum_k hbuf[r][k] * W[k][c]   (W row-major [*, HH], k = 0..127)
__device__ __forceinline__ void mm_lds(const float* __restrict__ hbuf,
                                       const float* __restrict__ W,
                                       int c, float acc[PP])
{
  for (int kt = 0; kt < HH / 4; kt++) {
    const float* wp = W + (kt * 4) * HH + c;
    const float w0 = wp[0];
    const float w1 = wp[HH];
    const float w2 = wp[2 * HH];
    const float w3 = wp[3 * HH];
#pragma unroll
    for (int r = 0; r < PP; r++) {
      const float4 v = *reinterpret_cast<const float4*>(hbuf + r * HP + kt * 4);
      acc[r] = fmaf(v.x, w0, fmaf(v.y, w1, fmaf(v.z, w2, fmaf(v.w, w3, acc[r]))));
    }
  }
}

// sum_k vbuf[k] * W[k*ldw + c], k = 0..127 (vbuf is an LDS vector, broadcast reads)
__device__ __forceinline__ float vec_dot(const float* __restrict__ vbuf,
                                         const float* __restrict__ W,
                                         int ldw, int c)
{
  float s = 0.f;
  for (int kt = 0; kt < HH / 4; kt++) {
    const float4 v = *reinterpret_cast<const float4*>(vbuf + kt * 4);
    const float* wp = W + (kt * 4) * ldw + c;
    s = fmaf(v.x, wp[0], s);
    s = fmaf(v.y, wp[ldw], s);
    s = fmaf(v.z, wp[2 * ldw], s);
    s = fmaf(v.w, wp[3 * ldw], s);
  }
  return s;
}

// LN (+ReLU, optional mask, optional max-pool into pl) over acc[PP] / hbuf.
__device__ __forceinline__ void ln_block(float acc[PP], float* __restrict__ hbuf,
                                         float* __restrict__ stats,
                                         const float* __restrict__ G,
                                         const float* __restrict__ BE,
                                         const float* __restrict__ mf,
                                         bool domask, float* __restrict__ pl, int c)
{
  __syncthreads();               // prior readers of hbuf done
#pragma unroll
  for (int r = 0; r < PP; r++) hbuf[r * HP + c] = acc[r];
  __syncthreads();               // hbuf visible to stats lanes
  ln_stats(hbuf, stats, c);
  __syncthreads();               // stats visible; hbuf free to overwrite
  const float gg = G[c], bb = BE[c];
  float pmax = 0.f;
#pragma unroll
  for (int r = 0; r < PP; r++) {
    float v = fmaf((acc[r] - stats[2 * r]) * stats[2 * r + 1], gg, bb);
    v = fmaxf(v, 0.f);
    if (domask) v *= mf[r];
    acc[r] = v;
    hbuf[r * HP + c] = v;
    pmax = fmaxf(pmax, v);
  }
  if (domask) pl[c] = pmax;
  __syncthreads();               // hbuf (+pl) visible for next stage
}

extern "C" __global__ void __launch_bounds__(128, 4)
polyline_fused(const float* __restrict__ poly, const int* __restrict__ mask,
               const float* __restrict__ W1,  const float* __restrict__ b1,
               const float* __restrict__ g1,  const float* __restrict__ be1,
               const float* __restrict__ W2,  const float* __restrict__ b2,
               const float* __restrict__ g2,  const float* __restrict__ be2,
               const float* __restrict__ f2W1, const float* __restrict__ f2b1,
               const float* __restrict__ f2g1, const float* __restrict__ f2be1,
               const float* __restrict__ f2W2, const float* __restrict__ f2b2,
               const float* __restrict__ f2g2, const float* __restrict__ f2be2,
               const float* __restrict__ foW1, const float* __restrict__ fob1,
               const float* __restrict__ foW2, const float* __restrict__ fob2,
               float* __restrict__ out)
{
  __shared__ float xs[PP * CC];
  __shared__ float mf[PP];
  __shared__ float hbuf[PP * HP];
  __shared__ float stats[PP * 2];
  __shared__ float pl[HH];

  const int bn = blockIdx.x;
  const int c  = threadIdx.x;   // 0..127

  // stage input points + mask
  const float* xp = poly + (size_t)bn * (PP * CC);
  for (int i = c; i < PP * CC; i += 128) xs[i] = xp[i];
  if (c < PP) mf[c] = (mask[(size_t)bn * PP + c] != 0) ? 1.0f : 0.0f;
  __syncthreads();

  float validf = 0.f;
#pragma unroll
  for (int r = 0; r < PP; r++) validf += mf[r];
  validf = (validf > 0.f) ? 1.f : 0.f;

  float acc[PP];

  // ---- fc1 linear1: [20,13] @ [13,128] + b1
  {
    const float bb = b1[c];
#pragma unroll
    for (int r = 0; r < PP; r++) acc[r] = bb;
    for (int k = 0; k < CC; k++) {
      const float w = W1[k * HH + c];
#pragma unroll
      for (int r = 0; r < PP; r++) acc[r] = fmaf(xs[r * CC + k], w, acc[r]);
    }
  }

  // ---- LN1 + ReLU (no mask)
  ln_block(acc, hbuf, stats, g1, be1, mf, false, pl, c);

  // ---- fc1 linear2: [20,128] @ [128,128] + b2
  {
    const float bb = b2[c];
#pragma unroll
    for (int r = 0; r < PP; r++) acc[r] = bb;
    mm_lds(hbuf, W2, c, acc);
  }

  // ---- LN2 + ReLU, * mask -> feat (hbuf), pooled -> pl
  ln_block(acc, hbuf, stats, g2, be2, mf, true, pl, c);

  // ---- fc2 linear1: cat([feat, pooled]) [20,256] @ [256,128] + b1
  {
    // pooled part is row-independent: rows 128..255 of f2W1
    const float pc = vec_dot(pl, f2W1 + HH * HH, HH, c);
    const float bb = f2b1[c] + pc;
#pragma unroll
    for (int r = 0; r < PP; r++) acc[r] = bb;
    mm_lds(hbuf, f2W1, c, acc);
  }

  // ---- LN3 + ReLU (no mask)
  ln_block(acc, hbuf, stats, f2g1, f2be1, mf, false, pl, c);

  // ---- fc2 linear2: [20,128] @ [128,128] + b2
  {
    const float bb = f2b2[c];
#pragma unroll
    for (int r = 0; r < PP; r++) acc[r] = bb;
    mm_lds(hbuf, f2W2, c, acc);
  }

  // ---- LN4 + ReLU, * mask -> feat2; pooled2 -> pl
  ln_block(acc, hbuf, stats, f2g2, f2be2, mf, true, pl, c);

  // ---- fc_out linear1 + ReLU: pooled2 [128] @ [128,128]
  {
    float z = fob1[c] + vec_dot(pl, foW1, HH, c);
    z = fmaxf(z, 0.f);
    hbuf[c] = z;                 // reuse hbuf[0..127] as z vector
  }
  __syncthreads();

  // ---- fc_out linear2: z [128] @ [128,256] + b2, * valid
  {
    float o0 = fob2[c];
    float o1 = fob2[c + HH];
    for (int kt = 0; kt < HH / 4; kt++) {
      const float4 v = *reinterpret_cast<const float4*>(hbuf + kt * 4);
      const float* wp = foW2 + (kt * 4) * OO + c;
      o0 = fmaf(v.x, wp[0], o0);
      o0 = fmaf(v.y, wp[OO], o0);
      o0 = fmaf(v.z, wp[2 * OO], o0);
      o0 = fmaf(v.w, wp[3 * OO], o0);
      const float* wq = wp + HH;
      o1 = fmaf(v.x, wq[0], o1);
      o1 = fmaf(v.y, wq[OO], o1);
      o1 = fmaf(v.z, wq[2 * OO], o1);
      o1 = fmaf(v.w, wq[3 * OO], o1);
    }
    float* op = out + (size_t)bn * OO;
    op[c]      = o0 * validf;
    op[c + HH] = o1 * validf;
  }
}

extern "C" void kernel_launch(void* const* d_in, const int* in_sizes, int n_in,
                              void* d_out, int out_size, void* d_ws, size_t ws_size,
                              hipStream_t stream)
{
  const float* poly  = (const float*)d_in[0];
  const int*   mask  = (const int*)d_in[1];
  const float* W1    = (const float*)d_in[2];
  const float* b1    = (const float*)d_in[3];
  const float* g1    = (const float*)d_in[4];
  const float* be1   = (const float*)d_in[5];
  const float* W2    = (const float*)d_in[6];
  const float* b2    = (const float*)d_in[7];
  const float* g2    = (const float*)d_in[8];
  const float* be2   = (const float*)d_in[9];
  const float* f2W1  = (const float*)d_in[10];
  const float* f2b1  = (const float*)d_in[11];
  const float* f2g1  = (const float*)d_in[12];
  const float* f2be1 = (const float*)d_in[13];
  const float* f2W2  = (const float*)d_in[14];
  const float* f2b2  = (const float*)d_in[15];
  const float* f2g2  = (const float*)d_in[16];
  const float* f2be2 = (const float*)d_in[17];
  const float* foW1  = (const float*)d_in[18];
  const float* fob1  = (const float*)d_in[19];
  const float* foW2  = (const float*)d_in[20];
  const float* fob2  = (const float*)d_in[21];
  float* out = (float*)d_out;

  const int nbn = in_sizes[0] / (PP * CC);   // B*N = 16384 polylines

  polyline_fused<<<dim3(nbn), dim3(128), 0, stream>>>(
      poly, mask, W1, b1, g1, be1, W2, b2, g2, be2,
      f2W1, f2b1, f2g1, f2be1, f2W2, f2b2, f2g2, f2be2,
      foW1, fob1, foW2, fob2, out);
}

// Round 2
// 281.096 us; speedup vs baseline: 2.5928x; 2.5928x over previous
//
#include <hip/hip_runtime.h>
#include <math.h>

// PolylineNet fused fp16-MFMA kernel.
// Block = 8 polylines (M = 160 rows), 256 threads = 4 waves.
// Wave w owns N-tiles {2w, 2w+1} (cols 32w..32w+31) of every GEMM.
// A-operands in LDS fp16 [160][HSTR]; B-operands read as fragments from
// pre-transposed fp16 weights in d_ws ([N][K] row-major, L2-resident).
// LN in fp32 on accumulators; pooling via LDS int atomicMax on float bits.

#define PP 20
#define GG 8           // polylines per block
#define MM 160         // GG*PP rows
#define MT 10          // M-tiles of 16
#define HH 128
#define OO 256
#define HSTR 132       // LDS row stride in halves (264 B)

typedef _Float16 f16x4 __attribute__((ext_vector_type(4)));
typedef _Float16 f16x8 __attribute__((ext_vector_type(8)));
typedef float    f32x4 __attribute__((ext_vector_type(4)));

__device__ __forceinline__ f32x4 splat4(float x) { f32x4 v = {x, x, x, x}; return v; }

// Load an 8-half MFMA operand fragment: k = base+{0..3} and base+16+{0..3}.
__device__ __forceinline__ f16x8 ldfrag(const _Float16* p)
{
  f16x8 r;
  f16x4* r4 = reinterpret_cast<f16x4*>(&r);
  r4[0] = *reinterpret_cast<const f16x4*>(p);
  r4[1] = *reinterpret_cast<const f16x4*>(p + 16);
  return r;
}

// Full-height GEMM: acc[mt][nt] += A[160xK] * B-frags from Wt[N][KLD] (global).
template<int KSTEPS, int KLD, bool INIT0>
__device__ __forceinline__ void gemm_tiles(const _Float16* __restrict__ Ah,
                                           const _Float16* __restrict__ Wt,
                                           f32x4 acc[MT][2], int l15, int lg, int w)
{
  f16x8 bfr[2][KSTEPS];
#pragma unroll
  for (int nt = 0; nt < 2; nt++) {
    const _Float16* bp = Wt + (size_t)((2 * w + nt) * 16 + l15) * KLD + 4 * lg;
#pragma unroll
    for (int ks = 0; ks < KSTEPS; ks++) bfr[nt][ks] = ldfrag(bp + 32 * ks);
  }
#pragma unroll
  for (int mt = 0; mt < MT; mt++) {
    if (INIT0) { acc[mt][0] = splat4(0.f); acc[mt][1] = splat4(0.f); }
    const _Float16* ap = Ah + (mt * 16 + l15) * HSTR + 4 * lg;
#pragma unroll
    for (int ks = 0; ks < KSTEPS; ks++) {
      f16x8 af = ldfrag(ap + 32 * ks);
      acc[mt][0] = __builtin_amdgcn_mfma_f32_16x16x32_f16(af, bfr[0][ks], acc[mt][0], 0, 0, 0);
      acc[mt][1] = __builtin_amdgcn_mfma_f32_16x16x32_f16(af, bfr[1][ks], acc[mt][1], 0, 0, 0);
    }
  }
}

// Single-M-tile GEMM (A = 16 rows in LDS), NT output tiles starting at ntbase.
template<int KSTEPS, int KLD, int NT>
__device__ __forceinline__ void gemm16(const _Float16* __restrict__ Ah,
                                       const _Float16* __restrict__ Wt,
                                       f32x4* acc, int l15, int lg, int ntbase)
{
  f16x8 af[KSTEPS];
#pragma unroll
  for (int ks = 0; ks < KSTEPS; ks++)
    af[ks] = ldfrag(Ah + l15 * HSTR + 4 * lg + 32 * ks);
#pragma unroll
  for (int nt = 0; nt < NT; nt++) {
    const _Float16* bp = Wt + (size_t)((ntbase + nt) * 16 + l15) * KLD + 4 * lg;
#pragma unroll
    for (int ks = 0; ks < KSTEPS; ks++) {
      f16x8 bf = ldfrag(bp + 32 * ks);
      acc[nt] = __builtin_amdgcn_mfma_f32_16x16x32_f16(af[ks], bf, acc[nt], 0, 0, 0);
    }
  }
}

// LN phase (a)+(b): optional bias add, then per-row {sum, sumsq} partials.
template<bool ADDB>
__device__ __forceinline__ void ln_partials(f32x4 acc[MT][2], const float* __restrict__ bias,
                                            float2* __restrict__ part, int l15, int lg, int w)
{
  float bb0 = 0.f, bb1 = 0.f;
  if (ADDB) { bb0 = bias[32 * w + l15]; bb1 = bias[32 * w + 16 + l15]; }
#pragma unroll
  for (int mt = 0; mt < MT; mt++) {
#pragma unroll
    for (int j = 0; j < 4; j++) {
      if (ADDB) { acc[mt][0][j] += bb0; acc[mt][1][j] += bb1; }
      float s = acc[mt][0][j] + acc[mt][1][j];
      float q = acc[mt][0][j] * acc[mt][0][j] + acc[mt][1][j] * acc[mt][1][j];
#pragma unroll
      for (int off = 1; off < 16; off <<= 1) {
        s += __shfl_xor(s, off, 64);
        q += __shfl_xor(q, off, 64);
      }
      if (l15 == 0) part[(mt * 16 + lg * 4 + j) * 4 + w] = make_float2(s, q);
    }
  }
}

__device__ __forceinline__ void ln_stats_c(const float2* __restrict__ part,
                                           float2* __restrict__ stats, int tid)
{
  if (tid < MM) {
    float s = 0.f, q = 0.f;
#pragma unroll
    for (int i = 0; i < 4; i++) { float2 p = part[tid * 4 + i]; s += p.x; q += p.y; }
    const float mu  = s * (1.0f / HH);
    const float var = q * (1.0f / HH) - mu * mu;
    stats[tid] = make_float2(mu, rsqrtf(var + 1e-5f));
  }
}

// LN phase (d): normalize in-register, optional mask/pool/LDS-writeback.
template<bool DOMASK, bool DOPOOL, bool DOWRITE>
__device__ __forceinline__ void ln_normalize(f32x4 acc[MT][2],
                                             const float* __restrict__ gamma,
                                             const float* __restrict__ beta,
                                             const float* __restrict__ mf,
                                             int* __restrict__ pmaxI,
                                             _Float16* __restrict__ Hh,
                                             const float2* __restrict__ stats,
                                             int l15, int lg, int w)
{
  const int c0 = 32 * w + l15, c1 = c0 + 16;
  const float gg0 = gamma[c0], be0 = beta[c0];
  const float gg1 = gamma[c1], be1 = beta[c1];
#pragma unroll
  for (int mt = 0; mt < MT; mt++) {
#pragma unroll
    for (int j = 0; j < 4; j++) {
      const int row = mt * 16 + lg * 4 + j;
      const float2 st = stats[row];
      float v0 = fmaxf(fmaf((acc[mt][0][j] - st.x) * st.y, gg0, be0), 0.f);
      float v1 = fmaxf(fmaf((acc[mt][1][j] - st.x) * st.y, gg1, be1), 0.f);
      if (DOMASK) { const float m = mf[row]; v0 *= m; v1 *= m; }
      if (DOWRITE) {
        Hh[row * HSTR + c0] = (_Float16)v0;
        Hh[row * HSTR + c1] = (_Float16)v1;
      }
      if (DOPOOL) {
        const int p = (unsigned)row / 20u;
        atomicMax(&pmaxI[p * HH + c0], __float_as_int(v0));
        atomicMax(&pmaxI[p * HH + c1], __float_as_int(v1));
      }
    }
  }
}

// ---- prep: transpose+convert all weights to fp16 [N][K] into d_ws ----
__global__ void prep_weights(const float* __restrict__ W1, const float* __restrict__ W2,
                             const float* __restrict__ F2W1, const float* __restrict__ F2W2,
                             const float* __restrict__ FO1, const float* __restrict__ FO2,
                             _Float16* __restrict__ wt)
{
  const int idx = blockIdx.x * 256 + threadIdx.x;
  if (idx >= 118784) return;
  float v;
  if (idx < 4096)        { int n = idx >> 5, k = idx & 31;            v = (k < 13) ? W1[k * 128 + n] : 0.f; }
  else if (idx < 20480)  { int j = idx - 4096;  int n = j >> 7, k = j & 127; v = W2[k * 128 + n]; }
  else if (idx < 36864)  { int j = idx - 20480; int n = j >> 7, k = j & 127; v = F2W1[k * 128 + n]; }
  else if (idx < 53248)  { int j = idx - 36864; int n = j >> 7, k = j & 127; v = F2W1[(128 + k) * 128 + n]; }
  else if (idx < 69632)  { int j = idx - 53248; int n = j >> 7, k = j & 127; v = F2W2[k * 128 + n]; }
  else if (idx < 86016)  { int j = idx - 69632; int n = j >> 7, k = j & 127; v = FO1[k * 128 + n]; }
  else                   { int j = idx - 86016; int n = j >> 7, k = j & 127; v = FO2[k * 256 + n]; }
  wt[idx] = (_Float16)v;
}

// ---- main fused kernel ----
extern "C" __global__ void __launch_bounds__(256, 2)
polynet_main(const float* __restrict__ poly, const int* __restrict__ maskp,
             const float* __restrict__ b1,  const float* __restrict__ g1,  const float* __restrict__ be1,
             const float* __restrict__ b2,  const float* __restrict__ g2,  const float* __restrict__ be2,
             const float* __restrict__ f2b1, const float* __restrict__ f2g1, const float* __restrict__ f2be1,
             const float* __restrict__ f2b2, const float* __restrict__ f2g2, const float* __restrict__ f2be2,
             const float* __restrict__ fob1, const float* __restrict__ fob2,
             const _Float16* __restrict__ wt, float* __restrict__ out)
{
  __shared__ _Float16 Hh[MM * HSTR];     // activations / GEMM A (42.2 KB)
  __shared__ float2   part[MM * 4];      // per-wave LN partials
  __shared__ float2   stats[MM];         // {mu, rsig} per row
  __shared__ int      pmaxI[GG * HH];    // pooled max (float bits)
  __shared__ float    pc[GG * HSTR];     // pooled-contrib + f2b1 bias, f32
  __shared__ _Float16 Ph[16 * HSTR];     // pooled fp16 (rows 8..15 zero)
  __shared__ _Float16 Zh[16 * HSTR];     // head z fp16 (rows 8..15 zero)
  __shared__ float    mf[MM];
  __shared__ float    vld[GG];

  const int tid  = threadIdx.x;
  const int lane = tid & 63;
  const int w    = tid >> 6;
  const int l15  = lane & 15;
  const int lg   = lane >> 4;
  const int blk  = blockIdx.x;

  const _Float16* W1t   = wt;
  const _Float16* W2t   = wt + 4096;
  const _Float16* F2W1a = wt + 20480;
  const _Float16* F2W1b = wt + 36864;
  const _Float16* F2W2t = wt + 53248;
  const _Float16* FOW1t = wt + 69632;
  const _Float16* FOW2t = wt + 86016;

  // ---- stage ----
  const float* xp = poly + (size_t)blk * (GG * PP * 13);
  for (int i = tid; i < GG * PP * 13; i += 256) {
    const int row = i / 13, k = i % 13;
    Hh[row * HSTR + k] = (_Float16)xp[i];
  }
  for (int i = tid; i < MM * 19; i += 256) {   // zero-pad k = 13..31
    const int row = i / 19, k = 13 + i % 19;
    Hh[row * HSTR + k] = (_Float16)0.f;
  }
  const int* mp = maskp + (size_t)blk * MM;
  for (int i = tid; i < MM; i += 256) mf[i] = mp[i] ? 1.f : 0.f;
  for (int i = tid; i < GG * HH; i += 256) pmaxI[i] = 0;
  for (int i = tid; i < 16 * HSTR; i += 256) { Ph[i] = (_Float16)0.f; Zh[i] = (_Float16)0.f; }
  __syncthreads();

  f32x4 acc[MT][2];

  // ---- GEMM1: X[160,32] @ W1t + LN1 ----
  gemm_tiles<1, 32, true>(Hh, W1t, acc, l15, lg, w);
  ln_partials<true>(acc, b1, part, l15, lg, w);
  __syncthreads();
  ln_stats_c(part, stats, tid);
  if (tid < GG) {
    float s = 0.f;
    for (int i = 0; i < PP; i++) s += mf[tid * PP + i];
    vld[tid] = (s > 0.f) ? 1.f : 0.f;
  }
  __syncthreads();
  ln_normalize<false, false, true>(acc, g1, be1, mf, pmaxI, Hh, stats, l15, lg, w);
  __syncthreads();

  // ---- GEMM2: H[160,128] @ W2t + LN2 (mask, pool) ----
  gemm_tiles<4, 128, true>(Hh, W2t, acc, l15, lg, w);
  ln_partials<true>(acc, b2, part, l15, lg, w);
  __syncthreads();
  ln_stats_c(part, stats, tid);
  __syncthreads();
  ln_normalize<true, true, true>(acc, g2, be2, mf, pmaxI, Hh, stats, l15, lg, w);
  __syncthreads();

  // ---- pooled -> Ph fp16 ----
  for (int i = tid; i < GG * HH; i += 256)
    Ph[(i >> 7) * HSTR + (i & 127)] = (_Float16)__int_as_float(pmaxI[i]);
  __syncthreads();

  // ---- pooled-GEMM: pc = f2b1 + pooled @ F2W1[128:256] ----
  {
    const int c0 = 32 * w + l15, c1 = c0 + 16;
    f32x4 accp[2];
    accp[0] = splat4(f2b1[c0]);
    accp[1] = splat4(f2b1[c1]);
    gemm16<4, 128, 2>(Ph, F2W1b, accp, l15, lg, 2 * w);
    if (lg < 2) {
#pragma unroll
      for (int j = 0; j < 4; j++) {
        const int p = lg * 4 + j;
        pc[p * HSTR + c0] = accp[0][j];
        pc[p * HSTR + c1] = accp[1][j];
      }
    }
  }
  __syncthreads();

  // ---- GEMM3: feat @ F2W1[0:128] + pc + LN3 ----
  {
    const int c0 = 32 * w + l15, c1 = c0 + 16;
#pragma unroll
    for (int mt = 0; mt < MT; mt++)
#pragma unroll
      for (int j = 0; j < 4; j++) {
        const int row = mt * 16 + lg * 4 + j;
        const unsigned p = (unsigned)row / 20u;
        acc[mt][0][j] = pc[p * HSTR + c0];
        acc[mt][1][j] = pc[p * HSTR + c1];
      }
  }
  gemm_tiles<4, 128, false>(Hh, F2W1a, acc, l15, lg, w);
  ln_partials<false>(acc, nullptr, part, l15, lg, w);
  __syncthreads();
  ln_stats_c(part, stats, tid);
  for (int i = tid; i < GG * HH; i += 256) pmaxI[i] = 0;   // re-zero for LN4 pool
  __syncthreads();
  ln_normalize<false, false, true>(acc, f2g1, f2be1, mf, pmaxI, Hh, stats, l15, lg, w);
  __syncthreads();

  // ---- GEMM4: h @ F2W2 + LN4 (mask, pool, no writeback) ----
  gemm_tiles<4, 128, true>(Hh, F2W2t, acc, l15, lg, w);
  ln_partials<true>(acc, f2b2, part, l15, lg, w);
  __syncthreads();
  ln_stats_c(part, stats, tid);
  __syncthreads();
  ln_normalize<true, true, false>(acc, f2g2, f2be2, mf, pmaxI, Hh, stats, l15, lg, w);
  __syncthreads();

  // ---- pooled2 -> Ph ----
  for (int i = tid; i < GG * HH; i += 256)
    Ph[(i >> 7) * HSTR + (i & 127)] = (_Float16)__int_as_float(pmaxI[i]);
  __syncthreads();

  // ---- head A: z = relu(pooled2 @ FOW1 + fob1) ----
  {
    const int c0 = 32 * w + l15, c1 = c0 + 16;
    f32x4 az[2];
    az[0] = splat4(fob1[c0]);
    az[1] = splat4(fob1[c1]);
    gemm16<4, 128, 2>(Ph, FOW1t, az, l15, lg, 2 * w);
    if (lg < 2) {
#pragma unroll
      for (int j = 0; j < 4; j++) {
        const int p = lg * 4 + j;
        Zh[p * HSTR + c0] = (_Float16)fmaxf(az[0][j], 0.f);
        Zh[p * HSTR + c1] = (_Float16)fmaxf(az[1][j], 0.f);
      }
    }
  }
  __syncthreads();

  // ---- head B: out = (z @ FOW2 + fob2) * valid ----
  {
    f32x4 ao[4];
#pragma unroll
    for (int nt = 0; nt < 4; nt++) {
      const int c = (4 * w + nt) * 16 + l15;
      ao[nt] = splat4(fob2[c]);
    }
    gemm16<4, 128, 4>(Zh, FOW2t, ao, l15, lg, 4 * w);
    if (lg < 2) {
#pragma unroll
      for (int nt = 0; nt < 4; nt++) {
        const int c = (4 * w + nt) * 16 + l15;
#pragma unroll
        for (int j = 0; j < 4; j++) {
          const int p = lg * 4 + j;
          out[((size_t)blk * GG + p) * OO + c] = ao[nt][j] * vld[p];
        }
      }
    }
  }
}

extern "C" void kernel_launch(void* const* d_in, const int* in_sizes, int n_in,
                              void* d_out, int out_size, void* d_ws, size_t ws_size,
                              hipStream_t stream)
{
  const float* poly  = (const float*)d_in[0];
  const int*   mask  = (const int*)d_in[1];
  const float* W1    = (const float*)d_in[2];
  const float* b1    = (const float*)d_in[3];
  const float* g1    = (const float*)d_in[4];
  const float* be1   = (const float*)d_in[5];
  const float* W2    = (const float*)d_in[6];
  const float* b2    = (const float*)d_in[7];
  const float* g2    = (const float*)d_in[8];
  const float* be2   = (const float*)d_in[9];
  const float* f2W1  = (const float*)d_in[10];
  const float* f2b1  = (const float*)d_in[11];
  const float* f2g1  = (const float*)d_in[12];
  const float* f2be1 = (const float*)d_in[13];
  const float* f2W2  = (const float*)d_in[14];
  const float* f2b2  = (const float*)d_in[15];
  const float* f2g2  = (const float*)d_in[16];
  const float* f2be2 = (const float*)d_in[17];
  const float* foW1  = (const float*)d_in[18];
  const float* fob1  = (const float*)d_in[19];
  const float* foW2  = (const float*)d_in[20];
  const float* fob2  = (const float*)d_in[21];
  float* out = (float*)d_out;

  _Float16* wt = (_Float16*)d_ws;           // 237,568 B of fp16 weights

  prep_weights<<<dim3((118784 + 255) / 256), dim3(256), 0, stream>>>(
      W1, W2, f2W1, f2W2, foW1, foW2, wt);

  const int npoly = in_sizes[0] / (PP * 13);   // 16384
  const int nblk  = npoly / GG;                // 2048

  polynet_main<<<dim3(nblk), dim3(256), 0, stream>>>(
      poly, mask, b1, g1, be1, b2, g2, be2,
      f2b1, f2g1, f2be1, f2b2, f2g2, f2be2,
      fob1, fob2, wt, out);
}